// Round 4
// baseline (355.549 us; speedup 1.0000x reference)
//
#include <hip/hip_runtime.h>

#define SZ 8192
#define WT_BYTES ((size_t)128 * 16384 * 2)     // 4 MB of bf16 transposed weights
#define H1_BYTES ((size_t)4096 * 8192 * 2)     // 64 MB bf16 h1 (swizzled layout)

typedef short short8 __attribute__((ext_vector_type(8)));
typedef float f32x4 __attribute__((ext_vector_type(4)));

static __device__ __forceinline__ unsigned short f2bf(float f){
    unsigned u = __float_as_uint(f);
    u += 0x7fffu + ((u >> 16) & 1u);          // RNE
    return (unsigned short)(u >> 16);
}

// ================= weight transpose (needs ws_size >= 4MB) =================
__global__ __launch_bounds__(256) void Monarch_prep(const float* __restrict__ w1,
                                                    const float* __restrict__ w2,
                                                    unsigned short* __restrict__ wt)
{
    __shared__ unsigned short T[128][132];
    int blk = blockIdx.x;
    const float* src = (blk < 64) ? (w1 + (size_t)blk * 16384)
                                  : (w2 + (size_t)(blk - 64) * 16384);
    unsigned short* dst = wt + (size_t)blk * 16384;
    int i  = threadIdx.x;
    int cs = i >> 5;
    int p0 = (i & 31) * 4;
    for (int rr = 0; rr < 16; ++rr){
        int c = rr * 8 + cs;
        f32x4 v = *(const f32x4*)(src + c * 128 + p0);
        T[p0 + 0][c] = f2bf(v[0]);
        T[p0 + 1][c] = f2bf(v[1]);
        T[p0 + 2][c] = f2bf(v[2]);
        T[p0 + 3][c] = f2bf(v[3]);
    }
    __syncthreads();
    for (int rr = 0; rr < 16; ++rr){
        int d = rr * 8 + cs;
        ushort4 o;
        o.x = T[d][p0 + 0]; o.y = T[d][p0 + 1]; o.z = T[d][p0 + 2]; o.w = T[d][p0 + 3];
        *(ushort4*)(dst + d * 128 + p0) = o;
    }
}

// ================= two-pass fast path (needs ws >= 68 MB) =================
// Pass A: stage-1 only (round-3 math verbatim), then linear dump of the
// swizzled LDS h1 buffer to workspace. No accumulator pressure -> register
// headroom for deep load pipelining (+ unroll 2 across jt).
__global__ __launch_bounds__(512, 2) void Monarch_s1(const float* __restrict__ x,
                                                     const unsigned short* __restrict__ w1T,
                                                     unsigned short* __restrict__ h1p)
{
    __shared__ __align__(16) unsigned short s[32 * 2048];   // 128 KB

    int b     = blockIdx.x;          // 512 blocks
    int xcd   = b & 7;
    int local = b >> 3;
    int g     = local & 3;
    int tgrp  = (xcd << 4) | (local >> 2);
    int t0    = tgrp << 5;
    int d0    = g << 5;

    int tid = threadIdx.x;
    int w   = tid >> 6;
    int l   = tid & 63;
    int m   = l & 15;
    int q   = l >> 4;

    const float* xrow0 = x + (size_t)(t0 + m) * SZ + q * 8;
    const float* xrow1 = xrow0 + (size_t)16 * SZ;
    #pragma unroll 2
    for (int jt = 0; jt < 8; ++jt){
        int j = (jt << 3) | w;
        f32x4 acc00 = {0.f,0.f,0.f,0.f}, acc01 = {0.f,0.f,0.f,0.f};
        f32x4 acc10 = {0.f,0.f,0.f,0.f}, acc11 = {0.f,0.f,0.f,0.f};
        const float* xp0 = xrow0 + j * 128;
        const float* xp1 = xrow1 + j * 128;
        const unsigned short* w1p = w1T + ((size_t)(j * 128 + d0 + m)) * 128 + q * 8;
        #pragma unroll
        for (int ko = 0; ko < 4; ++ko){
            short8 b0 = *(const short8*)(w1p + ko * 32);
            short8 b1 = *(const short8*)(w1p + 16 * 128 + ko * 32);
            f32x4 xa0 = *(const f32x4*)(xp0 + ko * 32);
            f32x4 xb0 = *(const f32x4*)(xp0 + ko * 32 + 4);
            f32x4 xa1 = *(const f32x4*)(xp1 + ko * 32);
            f32x4 xb1 = *(const f32x4*)(xp1 + ko * 32 + 4);
            short8 a0, a1;
            a0[0] = (short)f2bf(xa0[0]); a0[1] = (short)f2bf(xa0[1]);
            a0[2] = (short)f2bf(xa0[2]); a0[3] = (short)f2bf(xa0[3]);
            a0[4] = (short)f2bf(xb0[0]); a0[5] = (short)f2bf(xb0[1]);
            a0[6] = (short)f2bf(xb0[2]); a0[7] = (short)f2bf(xb0[3]);
            a1[0] = (short)f2bf(xa1[0]); a1[1] = (short)f2bf(xa1[1]);
            a1[2] = (short)f2bf(xa1[2]); a1[3] = (short)f2bf(xa1[3]);
            a1[4] = (short)f2bf(xb1[0]); a1[5] = (short)f2bf(xb1[1]);
            a1[6] = (short)f2bf(xb1[2]); a1[7] = (short)f2bf(xb1[3]);
            acc00 = __builtin_amdgcn_mfma_f32_16x16x32_bf16(a0, b0, acc00, 0, 0, 0);
            acc01 = __builtin_amdgcn_mfma_f32_16x16x32_bf16(a0, b1, acc01, 0, 0, 0);
            acc10 = __builtin_amdgcn_mfma_f32_16x16x32_bf16(a1, b0, acc10, 0, 0, 0);
            acc11 = __builtin_amdgcn_mfma_f32_16x16x32_bf16(a1, b1, acc11, 0, 0, 0);
        }
        #pragma unroll
        for (int r = 0; r < 4; ++r){
            int t   = q * 4 + r;
            int gc0 = 8 * m + jt;
            int gc1 = 8 * (16 + m) + jt;
            int gcs0 = gc0 ^ ((gc0 >> 3) & 7) ^ (t & 7);
            int gcs1 = gc1 ^ ((gc1 >> 3) & 7) ^ (t & 7);
            s[t * 2048 + gcs0 * 8 + w]        = f2bf(acc00[r]);
            s[t * 2048 + gcs1 * 8 + w]        = f2bf(acc01[r]);
            s[(t + 16) * 2048 + gcs0 * 8 + w] = f2bf(acc10[r]);
            s[(t + 16) * 2048 + gcs1 * 8 + w] = f2bf(acc11[r]);
        }
    }
    __syncthreads();

    // linear dump of the swizzled h1 LDS image: h1p[token][g][2048]
    unsigned short* hseg = h1p + (size_t)t0 * 8192 + g * 2048;
    #pragma unroll
    for (int it = 0; it < 16; ++it){
        int c = it * 512 + tid;          // c = t*256 + p
        int t = c >> 8;
        int p = c & 255;
        *(short8*)(hseg + (size_t)t * 8192 + p * 8) = *(const short8*)(s + c * 8);
    }
}

// Pass B: re-stage the swizzled h1 image linearly (async global_load_lds),
// then stage-2 + epilogue (round-3 math verbatim).
__global__ __launch_bounds__(512, 2) void Monarch_s2(const unsigned short* __restrict__ h1p,
                                                     const unsigned short* __restrict__ w2T,
                                                     const float* __restrict__ bias,
                                                     float* __restrict__ out)
{
    __shared__ __align__(16) unsigned short s[32 * 2048];   // 128 KB

    int b     = blockIdx.x;          // 512 blocks
    int xcd   = b & 7;
    int local = b >> 3;
    int g     = local & 3;
    int tgrp  = (xcd << 4) | (local >> 2);
    int t0    = tgrp << 5;
    int k0    = g << 4;

    int tid = threadIdx.x;
    int w   = tid >> 6;
    int l   = tid & 63;
    int m   = l & 15;
    int q   = l >> 4;

    const unsigned short* hseg = h1p + (size_t)t0 * 8192 + g * 2048;

#if defined(__has_builtin)
#if __has_builtin(__builtin_amdgcn_global_load_lds)
#define MONARCH_ASYNC_STAGE 1
#endif
#endif
#ifdef MONARCH_ASYNC_STAGE
    {
        int c0w = w * 64;                // wave-uniform lane base
        #pragma unroll
        for (int it = 0; it < 16; ++it){
            int c0 = it * 512 + c0w;     // wave-uniform chunk base
            int c  = c0 + l;             // per-lane chunk
            int t  = c >> 8;
            int p  = c & 255;
            const unsigned short* gsrc = hseg + (size_t)t * 8192 + p * 8;
            __builtin_amdgcn_global_load_lds(
                (const __attribute__((address_space(1))) void*)gsrc,
                (__attribute__((address_space(3))) void*)(s + (size_t)c0 * 8),
                16, 0, 0);
        }
    }
#else
    #pragma unroll
    for (int it = 0; it < 16; ++it){
        int c = it * 512 + tid;
        int t = c >> 8;
        int p = c & 255;
        *(short8*)(s + c * 8) = *(const short8*)(hseg + (size_t)t * 8192 + p * 8);
    }
#endif
    __syncthreads();

    // ---------- stage 2: 16 k2-blocks, 2 per wave, each bb feeds 2 tiles ----------
    f32x4 acc[2][2][8];   // [ki][u][nt]
    #pragma unroll
    for (int ki = 0; ki < 2; ++ki)
        #pragma unroll
        for (int u = 0; u < 2; ++u)
            #pragma unroll
            for (int nt = 0; nt < 8; ++nt)
                acc[ki][u][nt] = (f32x4){0.f, 0.f, 0.f, 0.f};

    #pragma unroll
    for (int ki = 0; ki < 2; ++ki){
        int kl = w + (ki << 3);
        const unsigned short* w2p = w2T + ((size_t)((k0 + kl) * 128 + m)) * 128 + q * 8;
        #pragma unroll
        for (int ko = 0; ko < 4; ++ko){
            int gc  = kl * 16 + ko * 4 + q;
            int gcs = gc ^ ((gc >> 3) & 7) ^ (m & 7);
            short8 a0 = *(const short8*)(s + m * 2048 + gcs * 8);
            short8 a1 = *(const short8*)(s + (m + 16) * 2048 + gcs * 8);
            #pragma unroll
            for (int nt = 0; nt < 8; ++nt){
                short8 bb = *(const short8*)(w2p + nt * 16 * 128 + ko * 32);
                acc[ki][0][nt] = __builtin_amdgcn_mfma_f32_16x16x32_bf16(a0, bb, acc[ki][0][nt], 0, 0, 0);
                acc[ki][1][nt] = __builtin_amdgcn_mfma_f32_16x16x32_bf16(a1, bb, acc[ki][1][nt], 0, 0, 0);
            }
        }
    }
    __syncthreads();

    // ---------- epilogue: 4 half-tiles of 8 token rows ----------
    float* osb = (float*)s;
    #pragma unroll
    for (int u = 0; u < 2; ++u){
        #pragma unroll
        for (int h = 0; h < 2; ++h){
            if ((q >> 1) == h){
                int tb = (q & 1) * 4;
                #pragma unroll
                for (int ki = 0; ki < 2; ++ki){
                    int kl = w + (ki << 3);
                    #pragma unroll
                    for (int nt = 0; nt < 8; ++nt){
                        int n    = nt * 16 + m;
                        int colc = (n & 63) * 32 + 2 * kl + (n >> 6);
                        int gnum = colc >> 2;
                        #pragma unroll
                        for (int r = 0; r < 4; ++r){
                            int t  = tb + r;
                            int gs = gnum ^ ((gnum >> 3) & 7) ^ (t & 7);
                            osb[t * 2048 + gs * 4 + (colc & 3)] = acc[ki][u][nt][r];
                        }
                    }
                }
            }
            __syncthreads();
            {
                int tr = tid >> 6;
                int cl = tid & 63;
                size_t orow = (size_t)(t0 + u * 16 + 8 * h + tr) * SZ;
                #pragma unroll
                for (int f = 0; f < 8; ++f){
                    int colc = cl * 4 + f * 256;
                    int gnum = colc >> 2;
                    int gs   = gnum ^ ((gnum >> 3) & 7) ^ (tr & 7);
                    f32x4 v  = *(const f32x4*)(osb + tr * 2048 + gs * 4);
                    int gcol = ((colc >> 5) << 7) + (g << 5) + (colc & 31);
                    f32x4 bi = *(const f32x4*)(bias + gcol);
                    *(f32x4*)(out + orow + gcol) = v + bi;
                }
            }
            __syncthreads();
        }
    }
}

// ================= mid tier: fused round-3 kernel (4MB <= ws < 68MB) =================
__global__ __launch_bounds__(512, 2) void Monarch_main(const float* __restrict__ x,
                                                       const unsigned short* __restrict__ w1T,
                                                       const unsigned short* __restrict__ w2T,
                                                       const float* __restrict__ bias,
                                                       float* __restrict__ out)
{
    __shared__ __align__(16) unsigned short s[32 * 2048];

    int b     = blockIdx.x;
    int xcd   = b & 7;
    int local = b >> 3;
    int g     = local & 3;
    int tgrp  = (xcd << 4) | (local >> 2);
    int t0    = tgrp << 5;
    int k0    = g << 4;
    int d0    = g << 5;

    int tid = threadIdx.x;
    int w   = tid >> 6;
    int l   = tid & 63;
    int m   = l & 15;
    int q   = l >> 4;

    const float* xrow0 = x + (size_t)(t0 + m) * SZ + q * 8;
    const float* xrow1 = xrow0 + (size_t)16 * SZ;
    for (int jt = 0; jt < 8; ++jt){
        int j = (jt << 3) | w;
        f32x4 acc00 = {0.f,0.f,0.f,0.f}, acc01 = {0.f,0.f,0.f,0.f};
        f32x4 acc10 = {0.f,0.f,0.f,0.f}, acc11 = {0.f,0.f,0.f,0.f};
        const float* xp0 = xrow0 + j * 128;
        const float* xp1 = xrow1 + j * 128;
        const unsigned short* w1p = w1T + ((size_t)(j * 128 + d0 + m)) * 128 + q * 8;
        #pragma unroll
        for (int ko = 0; ko < 4; ++ko){
            short8 b0 = *(const short8*)(w1p + ko * 32);
            short8 b1 = *(const short8*)(w1p + 16 * 128 + ko * 32);
            f32x4 xa0 = *(const f32x4*)(xp0 + ko * 32);
            f32x4 xb0 = *(const f32x4*)(xp0 + ko * 32 + 4);
            f32x4 xa1 = *(const f32x4*)(xp1 + ko * 32);
            f32x4 xb1 = *(const f32x4*)(xp1 + ko * 32 + 4);
            short8 a0, a1;
            a0[0] = (short)f2bf(xa0[0]); a0[1] = (short)f2bf(xa0[1]);
            a0[2] = (short)f2bf(xa0[2]); a0[3] = (short)f2bf(xa0[3]);
            a0[4] = (short)f2bf(xb0[0]); a0[5] = (short)f2bf(xb0[1]);
            a0[6] = (short)f2bf(xb0[2]); a0[7] = (short)f2bf(xb0[3]);
            a1[0] = (short)f2bf(xa1[0]); a1[1] = (short)f2bf(xa1[1]);
            a1[2] = (short)f2bf(xa1[2]); a1[3] = (short)f2bf(xa1[3]);
            a1[4] = (short)f2bf(xb1[0]); a1[5] = (short)f2bf(xb1[1]);
            a1[6] = (short)f2bf(xb1[2]); a1[7] = (short)f2bf(xb1[3]);
            acc00 = __builtin_amdgcn_mfma_f32_16x16x32_bf16(a0, b0, acc00, 0, 0, 0);
            acc01 = __builtin_amdgcn_mfma_f32_16x16x32_bf16(a0, b1, acc01, 0, 0, 0);
            acc10 = __builtin_amdgcn_mfma_f32_16x16x32_bf16(a1, b0, acc10, 0, 0, 0);
            acc11 = __builtin_amdgcn_mfma_f32_16x16x32_bf16(a1, b1, acc11, 0, 0, 0);
        }
        #pragma unroll
        for (int r = 0; r < 4; ++r){
            int t   = q * 4 + r;
            int gc0 = 8 * m + jt;
            int gc1 = 8 * (16 + m) + jt;
            int gcs0 = gc0 ^ ((gc0 >> 3) & 7) ^ (t & 7);
            int gcs1 = gc1 ^ ((gc1 >> 3) & 7) ^ (t & 7);
            s[t * 2048 + gcs0 * 8 + w]        = f2bf(acc00[r]);
            s[t * 2048 + gcs1 * 8 + w]        = f2bf(acc01[r]);
            s[(t + 16) * 2048 + gcs0 * 8 + w] = f2bf(acc10[r]);
            s[(t + 16) * 2048 + gcs1 * 8 + w] = f2bf(acc11[r]);
        }
    }
    __syncthreads();

    f32x4 acc[2][2][8];
    #pragma unroll
    for (int ki = 0; ki < 2; ++ki)
        #pragma unroll
        for (int u = 0; u < 2; ++u)
            #pragma unroll
            for (int nt = 0; nt < 8; ++nt)
                acc[ki][u][nt] = (f32x4){0.f, 0.f, 0.f, 0.f};

    #pragma unroll
    for (int ki = 0; ki < 2; ++ki){
        int kl = w + (ki << 3);
        const unsigned short* w2p = w2T + ((size_t)((k0 + kl) * 128 + m)) * 128 + q * 8;
        #pragma unroll
        for (int ko = 0; ko < 4; ++ko){
            int gc  = kl * 16 + ko * 4 + q;
            int gcs = gc ^ ((gc >> 3) & 7) ^ (m & 7);
            short8 a0 = *(const short8*)(s + m * 2048 + gcs * 8);
            short8 a1 = *(const short8*)(s + (m + 16) * 2048 + gcs * 8);
            #pragma unroll
            for (int nt = 0; nt < 8; ++nt){
                short8 bb = *(const short8*)(w2p + nt * 16 * 128 + ko * 32);
                acc[ki][0][nt] = __builtin_amdgcn_mfma_f32_16x16x32_bf16(a0, bb, acc[ki][0][nt], 0, 0, 0);
                acc[ki][1][nt] = __builtin_amdgcn_mfma_f32_16x16x32_bf16(a1, bb, acc[ki][1][nt], 0, 0, 0);
            }
        }
    }
    __syncthreads();

    float* osb = (float*)s;
    #pragma unroll
    for (int u = 0; u < 2; ++u){
        #pragma unroll
        for (int h = 0; h < 2; ++h){
            if ((q >> 1) == h){
                int tb = (q & 1) * 4;
                #pragma unroll
                for (int ki = 0; ki < 2; ++ki){
                    int kl = w + (ki << 3);
                    #pragma unroll
                    for (int nt = 0; nt < 8; ++nt){
                        int n    = nt * 16 + m;
                        int colc = (n & 63) * 32 + 2 * kl + (n >> 6);
                        int gnum = colc >> 2;
                        #pragma unroll
                        for (int r = 0; r < 4; ++r){
                            int t  = tb + r;
                            int gs = gnum ^ ((gnum >> 3) & 7) ^ (t & 7);
                            osb[t * 2048 + gs * 4 + (colc & 3)] = acc[ki][u][nt][r];
                        }
                    }
                }
            }
            __syncthreads();
            {
                int tr = tid >> 6;
                int cl = tid & 63;
                size_t orow = (size_t)(t0 + u * 16 + 8 * h + tr) * SZ;
                #pragma unroll
                for (int f = 0; f < 8; ++f){
                    int colc = cl * 4 + f * 256;
                    int gnum = colc >> 2;
                    int gs   = gnum ^ ((gnum >> 3) & 7) ^ (tr & 7);
                    f32x4 v  = *(const f32x4*)(osb + tr * 2048 + gs * 4);
                    int gcol = ((colc >> 5) << 7) + (g << 5) + (colc & 31);
                    f32x4 bi = *(const f32x4*)(bias + gcol);
                    *(f32x4*)(out + orow + gcol) = v + bi;
                }
            }
            __syncthreads();
        }
    }
}

// ================= fallback: fully fused, no d_ws =================
__global__ __launch_bounds__(256) void Monarch_fused(const float* __restrict__ x,
                                                     const float* __restrict__ w1,
                                                     const float* __restrict__ w2,
                                                     const float* __restrict__ bias,
                                                     float* __restrict__ out)
{
    __shared__ __align__(16) unsigned short s[16 * 2048];
    __shared__ __align__(16) unsigned short wst[4 * 5120];

    int b    = blockIdx.x;
    int g    = (b & 7) >> 1;
    int tile = ((b >> 3) << 1) | (b & 1);
    int t0   = tile << 4;
    int k0   = g << 4;
    int d0   = g << 5;

    int tid = threadIdx.x;
    int w   = tid >> 6;
    int l   = tid & 63;
    int m   = l & 15;
    int q   = l >> 4;

    unsigned short* wb = wst + w * 5120;
    int srow = l >> 3;
    int dcol = (l & 7) * 4;

    const float* xrow = x + (size_t)(t0 + m) * SZ + q * 8;
    for (int jt = 0; jt < 16; ++jt){
        int j = (jt << 2) | w;
        const float* wsrc = w1 + (size_t)j * 16384 + d0;
        #pragma unroll
        for (int rr = 0; rr < 16; ++rr){
            int c = rr * 8 + srow;
            f32x4 v = *(const f32x4*)(wsrc + c * 128 + dcol);
            #pragma unroll
            for (int i2 = 0; i2 < 4; ++i2)
                wb[(dcol + i2) * 136 + c] = (unsigned short)(__float_as_uint(v[i2]) >> 16);
        }
        f32x4 acc0 = {0.f, 0.f, 0.f, 0.f};
        f32x4 acc1 = {0.f, 0.f, 0.f, 0.f};
        const float* xp = xrow + j * 128;
        #pragma unroll
        for (int ko = 0; ko < 4; ++ko){
            f32x4 xa = *(const f32x4*)(xp + ko * 32);
            f32x4 xb = *(const f32x4*)(xp + ko * 32 + 4);
            short8 a;
            a[0] = (short)f2bf(xa[0]); a[1] = (short)f2bf(xa[1]);
            a[2] = (short)f2bf(xa[2]); a[3] = (short)f2bf(xa[3]);
            a[4] = (short)f2bf(xb[0]); a[5] = (short)f2bf(xb[1]);
            a[6] = (short)f2bf(xb[2]); a[7] = (short)f2bf(xb[3]);
            short8 b0 = *(const short8*)(wb + m * 136 + ko * 32 + q * 8);
            short8 b1 = *(const short8*)(wb + (m + 16) * 136 + ko * 32 + q * 8);
            acc0 = __builtin_amdgcn_mfma_f32_16x16x32_bf16(a, b0, acc0, 0, 0, 0);
            acc1 = __builtin_amdgcn_mfma_f32_16x16x32_bf16(a, b1, acc1, 0, 0, 0);
        }
        #pragma unroll
        for (int nt = 0; nt < 2; ++nt){
            int dl = nt * 16 + m;
            int gc = 8 * dl + (j >> 3);
            #pragma unroll
            for (int r = 0; r < 4; ++r){
                int t   = q * 4 + r;
                int gcs = gc ^ ((gc >> 3) & 7) ^ (t & 7);
                float v = nt ? acc1[r] : acc0[r];
                s[t * 2048 + gcs * 8 + (j & 7)] = f2bf(v);
            }
        }
    }
    __syncthreads();

    f32x4 acc[4][8];
    #pragma unroll
    for (int ki = 0; ki < 4; ++ki)
        #pragma unroll
        for (int nt = 0; nt < 8; ++nt)
            acc[ki][nt] = (f32x4){0.f, 0.f, 0.f, 0.f};

    for (int ki = 0; ki < 4; ++ki){
        int kl = w + (ki << 2);
        const float* w2src = w2 + (size_t)(k0 + kl) * 16384;
        #pragma unroll
        for (int ko = 0; ko < 4; ++ko){
            #pragma unroll
            for (int it = 0; it < 4; ++it){
                int cc = it * 8 + srow;
                const float* rp = w2src + (size_t)(ko * 32 + cc) * 128 + (l & 7) * 16;
                #pragma unroll
                for (int v4 = 0; v4 < 4; ++v4){
                    f32x4 v = *(const f32x4*)(rp + v4 * 4);
                    #pragma unroll
                    for (int i2 = 0; i2 < 4; ++i2)
                        wb[((l & 7) * 16 + v4 * 4 + i2) * 40 + cc] =
                            (unsigned short)(__float_as_uint(v[i2]) >> 16);
                }
            }
            int gc  = kl * 16 + ko * 4 + q;
            int gcs = gc ^ ((gc >> 3) & 7) ^ (m & 7);
            short8 a = *(const short8*)(s + m * 2048 + gcs * 8);
            #pragma unroll
            for (int nt = 0; nt < 8; ++nt){
                short8 bb = *(const short8*)(wb + (nt * 16 + m) * 40 + q * 8);
                acc[ki][nt] = __builtin_amdgcn_mfma_f32_16x16x32_bf16(a, bb, acc[ki][nt], 0, 0, 0);
            }
        }
    }
    __syncthreads();

    float* osb = (float*)s;
    for (int h = 0; h < 2; ++h){
        if ((q >> 1) == h){
            int tb = (q & 1) * 4;
            #pragma unroll
            for (int ki = 0; ki < 4; ++ki){
                int kl = w + (ki << 2);
                #pragma unroll
                for (int nt = 0; nt < 8; ++nt){
                    int n    = nt * 16 + m;
                    int colc = (n & 63) * 32 + 2 * kl + (n >> 6);
                    int gnum = colc >> 2;
                    #pragma unroll
                    for (int r = 0; r < 4; ++r){
                        int t  = tb + r;
                        int gs = gnum ^ ((gnum >> 3) & 7) ^ (t & 7);
                        osb[t * 2048 + gs * 4 + (colc & 3)] = acc[ki][nt][r];
                    }
                }
            }
        }
        __syncthreads();
        {
            int tr = tid >> 5;
            int cl = tid & 31;
            size_t orow = (size_t)(t0 + 8 * h + tr) * SZ;
            #pragma unroll
            for (int f = 0; f < 16; ++f){
                int colc = cl * 4 + f * 128;
                int gnum = colc >> 2;
                int gs   = gnum ^ ((gnum >> 3) & 7) ^ (tr & 7);
                f32x4 v  = *(const f32x4*)(osb + tr * 2048 + gs * 4);
                int gcol = ((colc >> 5) << 7) + (g << 5) + (colc & 31);
                f32x4 bi = *(const f32x4*)(bias + gcol);
                *(f32x4*)(out + orow + gcol) = v + bi;
            }
        }
        __syncthreads();
    }
}

extern "C" void kernel_launch(void* const* d_in, const int* in_sizes, int n_in,
                              void* d_out, int out_size, void* d_ws, size_t ws_size,
                              hipStream_t stream) {
    (void)in_sizes; (void)n_in; (void)out_size;
    const float* x    = (const float*)d_in[0];
    const float* w1   = (const float*)d_in[1];
    const float* w2   = (const float*)d_in[2];
    const float* bias = (const float*)d_in[3];

    if (ws_size >= WT_BYTES + H1_BYTES) {
        // two-pass fast path: per-phase isolation + register headroom + async staging
        unsigned short* wt  = (unsigned short*)d_ws;
        unsigned short* h1p = wt + (size_t)128 * 16384;
        Monarch_prep<<<dim3(128), dim3(256), 0, stream>>>(w1, w2, wt);
        Monarch_s1<<<dim3(512), dim3(512), 0, stream>>>(x, wt, h1p);
        Monarch_s2<<<dim3(512), dim3(512), 0, stream>>>(h1p, wt + (size_t)64 * 16384,
                                                        bias, (float*)d_out);
    } else if (ws_size >= WT_BYTES) {
        // mid tier: validated round-3 fused kernel
        unsigned short* wt = (unsigned short*)d_ws;
        Monarch_prep<<<dim3(128), dim3(256), 0, stream>>>(w1, w2, wt);
        Monarch_main<<<dim3(512), dim3(512), 0, stream>>>(x, wt, wt + (size_t)64 * 16384,
                                                          bias, (float*)d_out);
    } else {
        // fallback: fused, workspace-free
        Monarch_fused<<<dim3(1024), dim3(256), 0, stream>>>(x, w1, w2, bias, (float*)d_out);
    }
}